// Round 8
// baseline (733.497 us; speedup 1.0000x reference)
//
#include <hip/hip_runtime.h>
#include <hip/hip_bf16.h>
#include <stdint.h>

typedef __bf16 bf16x8 __attribute__((ext_vector_type(8)));
typedef __bf16 bf16x4 __attribute__((ext_vector_type(4)));
typedef float  f32x4  __attribute__((ext_vector_type(4)));

#define B_  16
#define KL  4096
#define D_  1024
#define NH  16
#define NROWS (B_*KL)   // 65536

__device__ __forceinline__ void gload_lds16(const void* g, void* l) {
  __builtin_amdgcn_global_load_lds(
      (__attribute__((address_space(1))) void*)g,
      (__attribute__((address_space(3))) void*)l, 16, 0, 0);
}

// ---------- small prep kernels ----------

__global__ __launch_bounds__(256) void conv_bf16_kernel(const float* __restrict__ s,
                                                        __bf16* __restrict__ d, int n4) {
  int i = blockIdx.x * 256 + threadIdx.x;
  if (i >= n4) return;
  float4 v = reinterpret_cast<const float4*>(s)[i];
  bf16x4 o;
  o[0] = (__bf16)v.x; o[1] = (__bf16)v.y; o[2] = (__bf16)v.z; o[3] = (__bf16)v.w;
  *reinterpret_cast<bf16x4*>(d + (size_t)i * 4) = o;
}

// q[b][j] = (hs[b,:]·Wq[j,:] + bq[j]) / 8
__global__ __launch_bounds__(256) void qproj_kernel(const float* __restrict__ hs,
                                                    const float* __restrict__ Wq,
                                                    const float* __restrict__ bq,
                                                    float* __restrict__ q) {
  int gid = blockIdx.x * 256 + threadIdx.x;   // 0..16383
  int b = gid >> 10, j = gid & 1023;
  const float* x = hs + (size_t)b * D_;
  const float* w = Wq + (size_t)j * D_;
  float acc = 0.f;
  for (int i = 0; i < D_; i += 4) {
    float4 xv = *reinterpret_cast<const float4*>(x + i);
    float4 wv = *reinterpret_cast<const float4*>(w + i);
    acc += xv.x*wv.x + xv.y*wv.y + xv.z*wv.z + xv.w*wv.w;
  }
  q[gid] = (acc + bq[j]) * 0.125f;
}

// wq_eff[b,h,m] = sum_d q[b,h*64+d] * Wk[h*64+d, m];  cb[b,h] = sum_d q*bk
__global__ __launch_bounds__(256) void wqeff_kernel(const float* __restrict__ q,
                                                    const float* __restrict__ Wk,
                                                    const float* __restrict__ bk,
                                                    float* __restrict__ wqe,
                                                    float* __restrict__ cb) {
  const int h = blockIdx.x, b = blockIdx.y;
  const int tid = threadIdx.x;
  __shared__ float ql[64];
  if (tid < 64) ql[tid] = q[(size_t)b * D_ + h * 64 + tid];
  __syncthreads();
  float a0 = 0, a1 = 0, a2 = 0, a3 = 0;
  for (int d = 0; d < 64; ++d) {
    float qv = ql[d];
    const float* wr = Wk + (size_t)(h * 64 + d) * D_;
    a0 += qv * wr[tid];
    a1 += qv * wr[tid + 256];
    a2 += qv * wr[tid + 512];
    a3 += qv * wr[tid + 768];
  }
  float* o = wqe + ((size_t)b * NH + h) * D_;
  o[tid] = a0; o[tid + 256] = a1; o[tid + 512] = a2; o[tid + 768] = a3;
  if (tid < 64) {
    float p = ql[tid] * bk[h * 64 + tid];
    p += __shfl_down(p, 32); p += __shfl_down(p, 16); p += __shfl_down(p, 8);
    p += __shfl_down(p, 4);  p += __shfl_down(p, 2);  p += __shfl_down(p, 1);
    if (tid == 0) cb[b * NH + h] = p;
  }
}

// attn[row][h] = clip(kvs[row,:]·wq_eff[b,h,:] + cb[b,h], 0, 1)  -- all f32
// FUSED: also emits kvs as bf16 (lane h==0 of each 16-lane head group stores
// the float4 it just loaded). Bit-identical to the old conv_kvs output.
__global__ __launch_bounds__(256) void scores_kernel(const float* __restrict__ kvs,
                                                     const float* __restrict__ wqe,
                                                     const float* __restrict__ cb,
                                                     float* __restrict__ attn,
                                                     __bf16* __restrict__ kvd) {
  __shared__ float4 wq4[NH * 256];   // 64 KiB, float4-slot XOR-swizzled by head
  const int b = blockIdx.y;
  const int chunk = blockIdx.x;      // 64 rows per block
  const int tid = threadIdx.x;
  for (int i = tid; i < NH * 256; i += 256) {
    int h = i >> 8, i4 = i & 255;
    wq4[h * 256 + (i4 ^ h)] =
        reinterpret_cast<const float4*>(wqe + ((size_t)b * NH + h) * D_)[i4];
  }
  __syncthreads();
  const int lane = tid & 63, w = tid >> 6;
  const int h = lane & 15, qt = lane >> 4;   // lane = head + 16*quarter
  const float c = cb[b * NH + h];
  for (int g = 0; g < 4; ++g) {
    const int row0 = chunk * 64 + w * 16 + g * 4;
    const size_t grow = (size_t)b * KL + row0;
    const float* x = kvs + grow * D_;
    float a0 = 0, a1 = 0, a2 = 0, a3 = 0;
    for (int it = 0; it < 64; ++it) {
      const int i4 = qt * 64 + it;
      float4 wv = wq4[h * 256 + (i4 ^ h)];
      const float* xm = x + i4 * 4;
      float4 r0 = *reinterpret_cast<const float4*>(xm);
      float4 r1 = *reinterpret_cast<const float4*>(xm + D_);
      float4 r2 = *reinterpret_cast<const float4*>(xm + 2 * D_);
      float4 r3 = *reinterpret_cast<const float4*>(xm + 3 * D_);
      a0 += r0.x*wv.x + r0.y*wv.y + r0.z*wv.z + r0.w*wv.w;
      a1 += r1.x*wv.x + r1.y*wv.y + r1.z*wv.z + r1.w*wv.w;
      a2 += r2.x*wv.x + r2.y*wv.y + r2.z*wv.z + r2.w*wv.w;
      a3 += r3.x*wv.x + r3.y*wv.y + r3.z*wv.z + r3.w*wv.w;
      if (h == 0) {   // lanes 0,16,32,48: store bf16 copy (each float4 once)
        bf16x4 o0, o1, o2, o3;
        o0[0]=(__bf16)r0.x; o0[1]=(__bf16)r0.y; o0[2]=(__bf16)r0.z; o0[3]=(__bf16)r0.w;
        o1[0]=(__bf16)r1.x; o1[1]=(__bf16)r1.y; o1[2]=(__bf16)r1.z; o1[3]=(__bf16)r1.w;
        o2[0]=(__bf16)r2.x; o2[1]=(__bf16)r2.y; o2[2]=(__bf16)r2.z; o2[3]=(__bf16)r2.w;
        o3[0]=(__bf16)r3.x; o3[1]=(__bf16)r3.y; o3[2]=(__bf16)r3.z; o3[3]=(__bf16)r3.w;
        *reinterpret_cast<bf16x4*>(kvd + (grow    ) * D_ + i4 * 4) = o0;
        *reinterpret_cast<bf16x4*>(kvd + (grow + 1) * D_ + i4 * 4) = o1;
        *reinterpret_cast<bf16x4*>(kvd + (grow + 2) * D_ + i4 * 4) = o2;
        *reinterpret_cast<bf16x4*>(kvd + (grow + 3) * D_ + i4 * 4) = o3;
      }
    }
    a0 += __shfl_xor(a0, 16); a0 += __shfl_xor(a0, 32);
    a1 += __shfl_xor(a1, 16); a1 += __shfl_xor(a1, 32);
    a2 += __shfl_xor(a2, 16); a2 += __shfl_xor(a2, 32);
    a3 += __shfl_xor(a3, 16); a3 += __shfl_xor(a3, 32);
    if (qt == 0) {
      size_t base = grow * NH + h;
      attn[base         ] = fminf(fmaxf(a0 + c, 0.f), 1.f);
      attn[base +    NH ] = fminf(fmaxf(a1 + c, 0.f), 1.f);
      attn[base + 2 * NH] = fminf(fmaxf(a2 + c, 0.f), 1.f);
      attn[base + 3 * NH] = fminf(fmaxf(a3 + c, 0.f), 1.f);
    }
  }
}

// ---------- 256x256 / BK=64 bf16 MFMA GEMM, 4-phase/K-tile + counted vmcnt ----------
// C = A @ Bt^T. 512 threads = 8 waves (2M x 4N); wave output 128 rows x 64 cols
// (rows mh*128+wm*64+f*16, cols nh*128+wn*32+g*16). Phase = (mh, kk), 16 MFMA
// each; B fragments (bv) live in regs across the mh pair of a kk.
// Staging: every wave contributes 2 loads to EVERY half-tile (chunk = h*16 +
// wid*2 + j), so per-wave vmcnt ledgers are uniform. Per-tile issue order:
// q1:Bh0(t+1) q2:Bh1(t+1) q3:Ah0(t+1) q4:Ah1(t+1).
// Invariant: at tile-t start, outstanding = Ah1(t) (2 loads).
//   q1-end: outstanding {Ah1(t), Bh0(t+1)} -> vmcnt(2) retires Ah1(t).
//   q4-end: outstanding {B(t+1), Ah0(t+1), Ah1(t+1)} = 8 -> vmcnt(2) retires
//           B(t+1)+Ah0(t+1), keeps Ah1(t+1). Never vmcnt(0) mid-loop.
// T2 swizzle: LDS[R][slot s] holds global col-block s^(R&7); read slot k as
// k^(r16&7) (all fragment rows have R&7 == r16&7).
template <bool GATE>
__global__ __launch_bounds__(512, 2) void gemm_nt(const __bf16* __restrict__ A,
                                                  const __bf16* __restrict__ Bt,
                                                  const float* __restrict__ bias,
                                                  const float* __restrict__ gate,
                                                  void* __restrict__ Cp) {
  __shared__ __bf16 As[2][256 * 64];
  __shared__ __bf16 Bs[2][256 * 64];
  const int tid = threadIdx.x;
  const int lane = tid & 63, wid = tid >> 6;
  const int wm = wid >> 2, wn = wid & 3;           // 2 x 4 waves
  const int r16 = lane & 15, kgrp = lane >> 4;
  // bijective XCD swizzle: 1024 blocks, 8 XCDs, 128 blocks each
  const int bswz = (blockIdx.x & 7) * 128 + (blockIdx.x >> 3);
  const int m0 = (bswz >> 2) * 256;
  const int n0 = (bswz & 3) * 256;

  // staging: chunk c = 8 rows x 64 cols (1 KB); chunk c = h*16 + wid*2 + j.
  const int srow = lane >> 3;
  const int scol = ((lane & 7) ^ srow) * 8;        // pre-swizzled source col

  // swizzled ds_read slots (elems): slot(kk) = ((kk*4+kgrp) ^ (r16&7)) * 8
  const int sw0 = ((kgrp) ^ (r16 & 7)) * 8;
  const int sw1 = ((4 + kgrp) ^ (r16 & 7)) * 8;

  f32x4 acc[8][4] = {};   // [mh*4+f][nh*2+g]

#define STAGE_HALF(dstbuf, srcp, base0, h, k0)                                  \
  {                                                                             \
    _Pragma("unroll") for (int j = 0; j < 2; ++j) {                             \
      const int c = (h) * 16 + wid * 2 + j;                                     \
      gload_lds16((srcp) + (size_t)((base0) + c * 8 + srow) * D_ + (k0) + scol, \
                  &(dstbuf)[c * 512]);                                          \
    }                                                                           \
  }

#define LOAD_BV(Bb, sw)                                                         \
  _Pragma("unroll") for (int nh = 0; nh < 2; ++nh)                              \
    _Pragma("unroll") for (int g = 0; g < 2; ++g)                               \
      bv[nh * 2 + g] = *reinterpret_cast<const bf16x8*>(                        \
          &(Bb)[(nh * 128 + wn * 32 + g * 16 + r16) * 64 + (sw)]);

#define PHASE_MFMA(Ab, mh, sw)                                                  \
  {                                                                             \
    bf16x8 av[4];                                                               \
    _Pragma("unroll") for (int f = 0; f < 4; ++f)                               \
      av[f] = *reinterpret_cast<const bf16x8*>(                                 \
          &(Ab)[((mh) * 128 + wm * 64 + f * 16 + r16) * 64 + (sw)]);            \
    __builtin_amdgcn_s_setprio(1);                                              \
    _Pragma("unroll") for (int f = 0; f < 4; ++f)                               \
      _Pragma("unroll") for (int q = 0; q < 4; ++q)                             \
        acc[(mh) * 4 + f][q] = __builtin_amdgcn_mfma_f32_16x16x32_bf16(         \
            av[f], bv[q], acc[(mh) * 4 + f][q], 0, 0, 0);                       \
    __builtin_amdgcn_s_setprio(0);                                              \
  }

  // prologue: tile 0 = Bh0,Bh1,Ah0,Ah1; retire all but Ah1(0).
  STAGE_HALF(Bs[0], Bt, n0, 0, 0);
  STAGE_HALF(Bs[0], Bt, n0, 1, 0);
  STAGE_HALF(As[0], A,  m0, 0, 0);
  STAGE_HALF(As[0], A,  m0, 1, 0);
  asm volatile("s_waitcnt vmcnt(2)" ::: "memory");
  __builtin_amdgcn_s_barrier();

  const int NT = D_ / 64;   // 16
  for (int t = 0; t < NT; ++t) {
    __bf16* Ab = (t & 1) ? As[1] : As[0];
    __bf16* Bb = (t & 1) ? Bs[1] : Bs[0];
    __bf16* An = (t & 1) ? As[0] : As[1];
    __bf16* Bn = (t & 1) ? Bs[0] : Bs[1];
    const int k1 = (t + 1) * 64;
    bf16x8 bv[4];
    // ---- q1: (mh0, kk0); stage Bh0(t+1) ----
    if (t < NT - 1) STAGE_HALF(Bn, Bt, n0, 0, k1);
    LOAD_BV(Bb, sw0);
    PHASE_MFMA(Ab, 0, sw0);
    if (t < NT - 1) asm volatile("s_waitcnt vmcnt(2)" ::: "memory");  // retire Ah1(t)
    else            asm volatile("s_waitcnt vmcnt(0)" ::: "memory");
    __builtin_amdgcn_s_barrier();
    // ---- q2: (mh1, kk0); stage Bh1(t+1) ----
    if (t < NT - 1) STAGE_HALF(Bn, Bt, n0, 1, k1);
    PHASE_MFMA(Ab, 1, sw0);
    // ---- q3: (mh0, kk1); stage Ah0(t+1) ----
    if (t < NT - 1) STAGE_HALF(An, A, m0, 0, k1);
    LOAD_BV(Bb, sw1);
    PHASE_MFMA(Ab, 0, sw1);
    // ---- q4: (mh1, kk1); stage Ah1(t+1) ----
    if (t < NT - 1) STAGE_HALF(An, A, m0, 1, k1);
    PHASE_MFMA(Ab, 1, sw1);
    if (t < NT - 1) {
      asm volatile("s_waitcnt vmcnt(2)" ::: "memory");  // retire B(t+1)+Ah0(t+1)
      __builtin_amdgcn_s_barrier();
    }
  }

  // epilogue. C/D layout: col = lane&15, row = (lane>>4)*4 + reg
#pragma unroll
  for (int mh = 0; mh < 2; ++mh) {
#pragma unroll
    for (int f = 0; f < 4; ++f) {
      const int row0 = m0 + mh * 128 + wm * 64 + f * 16 + kgrp * 4;
#pragma unroll
      for (int nh = 0; nh < 2; ++nh) {
#pragma unroll
        for (int g = 0; g < 2; ++g) {
          const int col = n0 + nh * 128 + wn * 32 + g * 16 + r16;
          const float bc = bias[col];
          const int head = col >> 6;
          f32x4 v = acc[mh * 4 + f][nh * 2 + g];
#pragma unroll
          for (int r = 0; r < 4; ++r) {
            const int row = row0 + r;
            if constexpr (GATE) {
              float gg = gate[(size_t)row * NH + head];
              ((__bf16*)Cp)[(size_t)row * D_ + col] = (__bf16)((v[r] + bc) * gg);
            } else {
              ((float*)Cp)[(size_t)row * D_ + col] = v[r] + bc;
            }
          }
        }
      }
    }
  }
#undef STAGE_HALF
#undef LOAD_BV
#undef PHASE_MFMA
}

extern "C" void kernel_launch(void* const* d_in, const int* in_sizes, int n_in,
                              void* d_out, int out_size, void* d_ws, size_t ws_size,
                              hipStream_t stream) {
  const float* hs  = (const float*)d_in[0];   // [16,1,1024]
  const float* kvs = (const float*)d_in[1];   // [16,4096,1024]
  const float* Wq  = (const float*)d_in[2];
  const float* bq  = (const float*)d_in[3];
  const float* Wk  = (const float*)d_in[4];
  const float* bk  = (const float*)d_in[5];
  const float* Wv  = (const float*)d_in[6];
  const float* bv  = (const float*)d_in[7];
  const float* Wo  = (const float*)d_in[8];
  const float* bo  = (const float*)d_in[9];
  float* out = (float*)d_out;

  char* w = (char*)d_ws;
  __bf16* ctx  = (__bf16*)w;  w += (size_t)NROWS * D_ * 2;   // 128 MB gated context (bf16)
  float*  attn = (float*)w;   w += (size_t)NROWS * NH * 4;   // 4 MB gate [row][head]
  __bf16* WvB  = (__bf16*)w;  w += (size_t)D_ * D_ * 2;      // 2 MB
  __bf16* WoB  = (__bf16*)w;  w += (size_t)D_ * D_ * 2;      // 2 MB
  float*  wqe  = (float*)w;   w += (size_t)B_ * NH * D_ * 4; // 1 MB
  float*  qbuf = (float*)w;   w += (size_t)B_ * D_ * 4;      // 64 KB
  float*  cbuf = (float*)w;   w += B_ * NH * 4;              // 1 KB

  // bf16 copy of kvs lives in d_out (128 MB of its 256 MB); written by the
  // fused scores kernel, consumed by GEMM1, then fully overwritten by GEMM2's
  // epilogue. No cross-call state.
  __bf16* kvsB = (__bf16*)d_out;

  conv_bf16_kernel<<<1024, 256, 0, stream>>>(Wv, WvB, 262144);
  conv_bf16_kernel<<<1024, 256, 0, stream>>>(Wo, WoB, 262144);
  qproj_kernel<<<64, 256, 0, stream>>>(hs, Wq, bq, qbuf);
  wqeff_kernel<<<dim3(NH, B_), 256, 0, stream>>>(qbuf, Wk, bk, wqe, cbuf);
  scores_kernel<<<dim3(64, B_), 256, 0, stream>>>(kvs, wqe, cbuf, attn, kvsB);
  gemm_nt<true ><<<1024, 512, 0, stream>>>(kvsB, WvB, bv, attn, ctx);
  gemm_nt<false><<<1024, 512, 0, stream>>>(ctx, WoB, bo, (const float*)nullptr, (void*)out);
}

// Round 9
// 498.940 us; speedup vs baseline: 1.4701x; 1.4701x over previous
//
#include <hip/hip_runtime.h>
#include <hip/hip_bf16.h>
#include <stdint.h>

typedef __bf16 bf16x8 __attribute__((ext_vector_type(8)));
typedef __bf16 bf16x4 __attribute__((ext_vector_type(4)));
typedef float  f32x4  __attribute__((ext_vector_type(4)));

#define B_  16
#define KL  4096
#define D_  1024
#define NH  16
#define NROWS (B_*KL)   // 65536

__device__ __forceinline__ void gload_lds16(const void* g, void* l) {
  __builtin_amdgcn_global_load_lds(
      (__attribute__((address_space(1))) void*)g,
      (__attribute__((address_space(3))) void*)l, 16, 0, 0);
}

// ---------- small prep kernels ----------

__global__ __launch_bounds__(256) void conv_bf16_kernel(const float* __restrict__ s,
                                                        __bf16* __restrict__ d, int n4) {
  int i = blockIdx.x * 256 + threadIdx.x;
  if (i >= n4) return;
  float4 v = reinterpret_cast<const float4*>(s)[i];
  bf16x4 o;
  o[0] = (__bf16)v.x; o[1] = (__bf16)v.y; o[2] = (__bf16)v.z; o[3] = (__bf16)v.w;
  *reinterpret_cast<bf16x4*>(d + (size_t)i * 4) = o;
}

// q[b][j] = (hs[b,:]·Wq[j,:] + bq[j]) / 8
__global__ __launch_bounds__(256) void qproj_kernel(const float* __restrict__ hs,
                                                    const float* __restrict__ Wq,
                                                    const float* __restrict__ bq,
                                                    float* __restrict__ q) {
  int gid = blockIdx.x * 256 + threadIdx.x;   // 0..16383
  int b = gid >> 10, j = gid & 1023;
  const float* x = hs + (size_t)b * D_;
  const float* w = Wq + (size_t)j * D_;
  float acc = 0.f;
  for (int i = 0; i < D_; i += 4) {
    float4 xv = *reinterpret_cast<const float4*>(x + i);
    float4 wv = *reinterpret_cast<const float4*>(w + i);
    acc += xv.x*wv.x + xv.y*wv.y + xv.z*wv.z + xv.w*wv.w;
  }
  q[gid] = (acc + bq[j]) * 0.125f;
}

// wq_eff[b,h,m] = sum_d q[b,h*64+d] * Wk[h*64+d, m], emitted as bf16 hi/lo
// split (whi = bf16(x), wlo = bf16(x - whi)); cb[b,h] = sum_d q*bk.
__global__ __launch_bounds__(256) void wqeff_kernel(const float* __restrict__ q,
                                                    const float* __restrict__ Wk,
                                                    const float* __restrict__ bk,
                                                    __bf16* __restrict__ whi,
                                                    __bf16* __restrict__ wlo,
                                                    float* __restrict__ cb) {
  const int h = blockIdx.x, b = blockIdx.y;
  const int tid = threadIdx.x;
  __shared__ float ql[64];
  if (tid < 64) ql[tid] = q[(size_t)b * D_ + h * 64 + tid];
  __syncthreads();
  float a0 = 0, a1 = 0, a2 = 0, a3 = 0;
  for (int d = 0; d < 64; ++d) {
    float qv = ql[d];
    const float* wr = Wk + (size_t)(h * 64 + d) * D_;
    a0 += qv * wr[tid];
    a1 += qv * wr[tid + 256];
    a2 += qv * wr[tid + 512];
    a3 += qv * wr[tid + 768];
  }
  const size_t base = ((size_t)b * NH + h) * D_;
  float a[4] = {a0, a1, a2, a3};
#pragma unroll
  for (int j = 0; j < 4; ++j) {
    __bf16 hi = (__bf16)a[j];
    whi[base + j * 256 + tid] = hi;
    wlo[base + j * 256 + tid] = (__bf16)(a[j] - (float)hi);
  }
  if (tid < 64) {
    float p = ql[tid] * bk[h * 64 + tid];
    p += __shfl_down(p, 32); p += __shfl_down(p, 16); p += __shfl_down(p, 8);
    p += __shfl_down(p, 4);  p += __shfl_down(p, 2);  p += __shfl_down(p, 1);
    if (tid == 0) cb[b * NH + h] = p;
  }
}

// Scores via split-bf16 MFMA: score = k_hi·w_hi + k_hi·w_lo + k_lo·w_hi
// (f32-accurate to ~1e-3). Also stores k_hi == bf16(kvs) as kvsB (the exact
// conversion GEMM1 consumes). One wave = 16 rows x 16 heads, K=1024.
// A-frag: row = lane&15, k = (lane>>4)*8+i. C: col(head) = lane&15,
// row = (lane>>4)*4 + reg.
__global__ __launch_bounds__(256) void scores_mfma_kernel(
    const float* __restrict__ kvs,   // [B, KL, D]
    const __bf16* __restrict__ whi,  // [B*NH, D]
    const __bf16* __restrict__ wlo,  // [B*NH, D]
    const float* __restrict__ cb,    // [B*NH]
    float* __restrict__ attn,        // [B*KL, NH]
    __bf16* __restrict__ kvd) {      // [B*KL, D]
  const int b = blockIdx.y;
  const int tid = threadIdx.x;
  const int lane = tid & 63, wv = tid >> 6;       // 4 waves/block
  const int r16 = lane & 15, kgrp = lane >> 4;
  const int row0 = blockIdx.x * 64 + wv * 16;     // 16 rows per wave
  const size_t grow = (size_t)b * KL + row0;

  const float* xrow = kvs + (grow + r16) * D_ + kgrp * 8;
  __bf16*      krow = kvd + (grow + r16) * D_ + kgrp * 8;
  const __bf16* wh = whi + ((size_t)b * NH + r16) * D_ + kgrp * 8;
  const __bf16* wl = wlo + ((size_t)b * NH + r16) * D_ + kgrp * 8;

  f32x4 acc = {};
  for (int k0 = 0; k0 < D_; k0 += 32) {
    float4 x0 = *reinterpret_cast<const float4*>(xrow + k0);
    float4 x1 = *reinterpret_cast<const float4*>(xrow + k0 + 4);
    float xs[8] = {x0.x, x0.y, x0.z, x0.w, x1.x, x1.y, x1.z, x1.w};
    bf16x8 hi, lo;
#pragma unroll
    for (int i = 0; i < 8; ++i) {
      __bf16 h = (__bf16)xs[i];
      hi[i] = h;
      lo[i] = (__bf16)(xs[i] - (float)h);
    }
    *reinterpret_cast<bf16x8*>(krow + k0) = hi;   // kvsB = bf16(kvs), exact
    bf16x8 bh = *reinterpret_cast<const bf16x8*>(wh + k0);
    bf16x8 bl = *reinterpret_cast<const bf16x8*>(wl + k0);
    acc = __builtin_amdgcn_mfma_f32_16x16x32_bf16(hi, bh, acc, 0, 0, 0);
    acc = __builtin_amdgcn_mfma_f32_16x16x32_bf16(hi, bl, acc, 0, 0, 0);
    acc = __builtin_amdgcn_mfma_f32_16x16x32_bf16(lo, bh, acc, 0, 0, 0);
  }
  const float c = cb[b * NH + r16];               // head = r16 in C layout
#pragma unroll
  for (int r = 0; r < 4; ++r) {
    const int orow = row0 + kgrp * 4 + r;
    float s = acc[r] + c;
    attn[((size_t)b * KL + orow) * NH + r16] = fminf(fmaxf(s, 0.f), 1.f);
  }
}

// ---------- 256x256 / BK=64 bf16 MFMA GEMM, 4-phase/K-tile + counted vmcnt ----------
// (verified R7/R8 structure; see invariant comments)
template <bool GATE>
__global__ __launch_bounds__(512, 2) void gemm_nt(const __bf16* __restrict__ A,
                                                  const __bf16* __restrict__ Bt,
                                                  const float* __restrict__ bias,
                                                  const float* __restrict__ gate,
                                                  void* __restrict__ Cp) {
  __shared__ __bf16 As[2][256 * 64];
  __shared__ __bf16 Bs[2][256 * 64];
  const int tid = threadIdx.x;
  const int lane = tid & 63, wid = tid >> 6;
  const int wm = wid >> 2, wn = wid & 3;           // 2 x 4 waves
  const int r16 = lane & 15, kgrp = lane >> 4;
  const int bswz = (blockIdx.x & 7) * 128 + (blockIdx.x >> 3);
  const int m0 = (bswz >> 2) * 256;
  const int n0 = (bswz & 3) * 256;

  const int srow = lane >> 3;
  const int scol = ((lane & 7) ^ srow) * 8;        // pre-swizzled source col

  const int sw0 = ((kgrp) ^ (r16 & 7)) * 8;
  const int sw1 = ((4 + kgrp) ^ (r16 & 7)) * 8;

  f32x4 acc[8][4] = {};   // [mh*4+f][nh*2+g]

#define STAGE_HALF(dstbuf, srcp, base0, h, k0)                                  \
  {                                                                             \
    _Pragma("unroll") for (int j = 0; j < 2; ++j) {                             \
      const int c = (h) * 16 + wid * 2 + j;                                     \
      gload_lds16((srcp) + (size_t)((base0) + c * 8 + srow) * D_ + (k0) + scol, \
                  &(dstbuf)[c * 512]);                                          \
    }                                                                           \
  }

#define LOAD_BV(Bb, sw)                                                         \
  _Pragma("unroll") for (int nh = 0; nh < 2; ++nh)                              \
    _Pragma("unroll") for (int g = 0; g < 2; ++g)                               \
      bv[nh * 2 + g] = *reinterpret_cast<const bf16x8*>(                        \
          &(Bb)[(nh * 128 + wn * 32 + g * 16 + r16) * 64 + (sw)]);

#define PHASE_MFMA(Ab, mh, sw)                                                  \
  {                                                                             \
    bf16x8 av[4];                                                               \
    _Pragma("unroll") for (int f = 0; f < 4; ++f)                               \
      av[f] = *reinterpret_cast<const bf16x8*>(                                 \
          &(Ab)[((mh) * 128 + wm * 64 + f * 16 + r16) * 64 + (sw)]);            \
    __builtin_amdgcn_s_setprio(1);                                              \
    _Pragma("unroll") for (int f = 0; f < 4; ++f)                               \
      _Pragma("unroll") for (int q = 0; q < 4; ++q)                             \
        acc[(mh) * 4 + f][q] = __builtin_amdgcn_mfma_f32_16x16x32_bf16(         \
            av[f], bv[q], acc[(mh) * 4 + f][q], 0, 0, 0);                       \
    __builtin_amdgcn_s_setprio(0);                                              \
  }

  STAGE_HALF(Bs[0], Bt, n0, 0, 0);
  STAGE_HALF(Bs[0], Bt, n0, 1, 0);
  STAGE_HALF(As[0], A,  m0, 0, 0);
  STAGE_HALF(As[0], A,  m0, 1, 0);
  asm volatile("s_waitcnt vmcnt(2)" ::: "memory");
  __builtin_amdgcn_s_barrier();

  const int NT = D_ / 64;   // 16
  for (int t = 0; t < NT; ++t) {
    __bf16* Ab = (t & 1) ? As[1] : As[0];
    __bf16* Bb = (t & 1) ? Bs[1] : Bs[0];
    __bf16* An = (t & 1) ? As[0] : As[1];
    __bf16* Bn = (t & 1) ? Bs[0] : Bs[1];
    const int k1 = (t + 1) * 64;
    bf16x8 bv[4];
    if (t < NT - 1) STAGE_HALF(Bn, Bt, n0, 0, k1);
    LOAD_BV(Bb, sw0);
    PHASE_MFMA(Ab, 0, sw0);
    if (t < NT - 1) asm volatile("s_waitcnt vmcnt(2)" ::: "memory");
    else            asm volatile("s_waitcnt vmcnt(0)" ::: "memory");
    __builtin_amdgcn_s_barrier();
    if (t < NT - 1) STAGE_HALF(Bn, Bt, n0, 1, k1);
    PHASE_MFMA(Ab, 1, sw0);
    if (t < NT - 1) STAGE_HALF(An, A, m0, 0, k1);
    LOAD_BV(Bb, sw1);
    PHASE_MFMA(Ab, 0, sw1);
    if (t < NT - 1) STAGE_HALF(An, A, m0, 1, k1);
    PHASE_MFMA(Ab, 1, sw1);
    if (t < NT - 1) {
      asm volatile("s_waitcnt vmcnt(2)" ::: "memory");
      __builtin_amdgcn_s_barrier();
    }
  }

#pragma unroll
  for (int mh = 0; mh < 2; ++mh) {
#pragma unroll
    for (int f = 0; f < 4; ++f) {
      const int row0 = m0 + mh * 128 + wm * 64 + f * 16 + kgrp * 4;
#pragma unroll
      for (int nh = 0; nh < 2; ++nh) {
#pragma unroll
        for (int g = 0; g < 2; ++g) {
          const int col = n0 + nh * 128 + wn * 32 + g * 16 + r16;
          const float bc = bias[col];
          const int head = col >> 6;
          f32x4 v = acc[mh * 4 + f][nh * 2 + g];
#pragma unroll
          for (int r = 0; r < 4; ++r) {
            const int row = row0 + r;
            if constexpr (GATE) {
              float gg = gate[(size_t)row * NH + head];
              ((__bf16*)Cp)[(size_t)row * D_ + col] = (__bf16)((v[r] + bc) * gg);
            } else {
              ((float*)Cp)[(size_t)row * D_ + col] = v[r] + bc;
            }
          }
        }
      }
    }
  }
#undef STAGE_HALF
#undef LOAD_BV
#undef PHASE_MFMA
}

extern "C" void kernel_launch(void* const* d_in, const int* in_sizes, int n_in,
                              void* d_out, int out_size, void* d_ws, size_t ws_size,
                              hipStream_t stream) {
  const float* hs  = (const float*)d_in[0];   // [16,1,1024]
  const float* kvs = (const float*)d_in[1];   // [16,4096,1024]
  const float* Wq  = (const float*)d_in[2];
  const float* bq  = (const float*)d_in[3];
  const float* Wk  = (const float*)d_in[4];
  const float* bk  = (const float*)d_in[5];
  const float* Wv  = (const float*)d_in[6];
  const float* bv  = (const float*)d_in[7];
  const float* Wo  = (const float*)d_in[8];
  const float* bo  = (const float*)d_in[9];
  float* out = (float*)d_out;

  char* w = (char*)d_ws;
  __bf16* ctx  = (__bf16*)w;  w += (size_t)NROWS * D_ * 2;    // 128 MB gated context (bf16)
  float*  attn = (float*)w;   w += (size_t)NROWS * NH * 4;    // 4 MB gate [row][head]
  __bf16* WvB  = (__bf16*)w;  w += (size_t)D_ * D_ * 2;       // 2 MB
  __bf16* WoB  = (__bf16*)w;  w += (size_t)D_ * D_ * 2;       // 2 MB
  __bf16* whi  = (__bf16*)w;  w += (size_t)B_ * NH * D_ * 2;  // 512 KB
  __bf16* wlo  = (__bf16*)w;  w += (size_t)B_ * NH * D_ * 2;  // 512 KB
  float*  qbuf = (float*)w;   w += (size_t)B_ * D_ * 4;       // 64 KB
  float*  cbuf = (float*)w;   w += B_ * NH * 4;               // 1 KB

  // bf16 copy of kvs lives in d_out (128 MB of its 256 MB); written by
  // scores_mfma (== bf16(kvs) exactly), consumed by GEMM1, then fully
  // overwritten by GEMM2's epilogue. No cross-call state.
  __bf16* kvsB = (__bf16*)d_out;

  conv_bf16_kernel<<<1024, 256, 0, stream>>>(Wv, WvB, 262144);
  conv_bf16_kernel<<<1024, 256, 0, stream>>>(Wo, WoB, 262144);
  qproj_kernel<<<64, 256, 0, stream>>>(hs, Wq, bq, qbuf);
  wqeff_kernel<<<dim3(NH, B_), 256, 0, stream>>>(qbuf, Wk, bk, whi, wlo, cbuf);
  scores_mfma_kernel<<<dim3(KL / 64, B_), 256, 0, stream>>>(kvs, whi, wlo, cbuf, attn, kvsB);
  gemm_nt<true ><<<1024, 512, 0, stream>>>(kvsB, WvB, bv, attn, ctx);
  gemm_nt<false><<<1024, 512, 0, stream>>>(ctx, WoB, bo, (const float*)nullptr, (void*)out);
}

// Round 10
// 491.663 us; speedup vs baseline: 1.4919x; 1.0148x over previous
//
#include <hip/hip_runtime.h>
#include <hip/hip_bf16.h>
#include <stdint.h>

typedef __bf16 bf16x8 __attribute__((ext_vector_type(8)));
typedef __bf16 bf16x4 __attribute__((ext_vector_type(4)));
typedef float  f32x4  __attribute__((ext_vector_type(4)));

#define B_  16
#define KL  4096
#define D_  1024
#define NH  16
#define NROWS (B_*KL)   // 65536

__device__ __forceinline__ void gload_lds16(const void* g, void* l) {
  __builtin_amdgcn_global_load_lds(
      (__attribute__((address_space(1))) void*)g,
      (__attribute__((address_space(3))) void*)l, 16, 0, 0);
}

// ---------- small prep kernels ----------

__global__ __launch_bounds__(256) void conv_bf16_kernel(const float* __restrict__ s,
                                                        __bf16* __restrict__ d, int n4) {
  int i = blockIdx.x * 256 + threadIdx.x;
  if (i >= n4) return;
  float4 v = reinterpret_cast<const float4*>(s)[i];
  bf16x4 o;
  o[0] = (__bf16)v.x; o[1] = (__bf16)v.y; o[2] = (__bf16)v.z; o[3] = (__bf16)v.w;
  *reinterpret_cast<bf16x4*>(d + (size_t)i * 4) = o;
}

// q[b][j] = (hs[b,:]·Wq[j,:] + bq[j]) / 8
__global__ __launch_bounds__(256) void qproj_kernel(const float* __restrict__ hs,
                                                    const float* __restrict__ Wq,
                                                    const float* __restrict__ bq,
                                                    float* __restrict__ q) {
  int gid = blockIdx.x * 256 + threadIdx.x;   // 0..16383
  int b = gid >> 10, j = gid & 1023;
  const float* x = hs + (size_t)b * D_;
  const float* w = Wq + (size_t)j * D_;
  float acc = 0.f;
  for (int i = 0; i < D_; i += 4) {
    float4 xv = *reinterpret_cast<const float4*>(x + i);
    float4 wv = *reinterpret_cast<const float4*>(w + i);
    acc += xv.x*wv.x + xv.y*wv.y + xv.z*wv.z + xv.w*wv.w;
  }
  q[gid] = (acc + bq[j]) * 0.125f;
}

// wq_eff[b,h,m] = sum_d q[b,h*64+d] * Wk[h*64+d, m], emitted as bf16 hi/lo
// split (whi = bf16(x), wlo = bf16(x - whi)); cb[b,h] = sum_d q*bk.
__global__ __launch_bounds__(256) void wqeff_kernel(const float* __restrict__ q,
                                                    const float* __restrict__ Wk,
                                                    const float* __restrict__ bk,
                                                    __bf16* __restrict__ whi,
                                                    __bf16* __restrict__ wlo,
                                                    float* __restrict__ cb) {
  const int h = blockIdx.x, b = blockIdx.y;
  const int tid = threadIdx.x;
  __shared__ float ql[64];
  if (tid < 64) ql[tid] = q[(size_t)b * D_ + h * 64 + tid];
  __syncthreads();
  float a0 = 0, a1 = 0, a2 = 0, a3 = 0;
  for (int d = 0; d < 64; ++d) {
    float qv = ql[d];
    const float* wr = Wk + (size_t)(h * 64 + d) * D_;
    a0 += qv * wr[tid];
    a1 += qv * wr[tid + 256];
    a2 += qv * wr[tid + 512];
    a3 += qv * wr[tid + 768];
  }
  const size_t base = ((size_t)b * NH + h) * D_;
  float a[4] = {a0, a1, a2, a3};
#pragma unroll
  for (int j = 0; j < 4; ++j) {
    __bf16 hi = (__bf16)a[j];
    whi[base + j * 256 + tid] = hi;
    wlo[base + j * 256 + tid] = (__bf16)(a[j] - (float)hi);
  }
  if (tid < 64) {
    float p = ql[tid] * bk[h * 64 + tid];
    p += __shfl_down(p, 32); p += __shfl_down(p, 16); p += __shfl_down(p, 8);
    p += __shfl_down(p, 4);  p += __shfl_down(p, 2);  p += __shfl_down(p, 1);
    if (tid == 0) cb[b * NH + h] = p;
  }
}

// Scores via split-bf16 MFMA: score = k_hi·w_hi + k_hi·w_lo + k_lo·w_hi.
// Also stores k_hi == bf16(kvs) as kvsB. One wave = 16 rows x 16 heads.
__global__ __launch_bounds__(256) void scores_mfma_kernel(
    const float* __restrict__ kvs,   // [B, KL, D]
    const __bf16* __restrict__ whi,  // [B*NH, D]
    const __bf16* __restrict__ wlo,  // [B*NH, D]
    const float* __restrict__ cb,    // [B*NH]
    float* __restrict__ attn,        // [B*KL, NH]
    __bf16* __restrict__ kvd) {      // [B*KL, D]
  const int b = blockIdx.y;
  const int tid = threadIdx.x;
  const int lane = tid & 63, wv = tid >> 6;       // 4 waves/block
  const int r16 = lane & 15, kgrp = lane >> 4;
  const int row0 = blockIdx.x * 64 + wv * 16;     // 16 rows per wave
  const size_t grow = (size_t)b * KL + row0;

  const float* xrow = kvs + (grow + r16) * D_ + kgrp * 8;
  __bf16*      krow = kvd + (grow + r16) * D_ + kgrp * 8;
  const __bf16* wh = whi + ((size_t)b * NH + r16) * D_ + kgrp * 8;
  const __bf16* wl = wlo + ((size_t)b * NH + r16) * D_ + kgrp * 8;

  f32x4 acc = {};
  for (int k0 = 0; k0 < D_; k0 += 32) {
    float4 x0 = *reinterpret_cast<const float4*>(xrow + k0);
    float4 x1 = *reinterpret_cast<const float4*>(xrow + k0 + 4);
    float xs[8] = {x0.x, x0.y, x0.z, x0.w, x1.x, x1.y, x1.z, x1.w};
    bf16x8 hi, lo;
#pragma unroll
    for (int i = 0; i < 8; ++i) {
      __bf16 h = (__bf16)xs[i];
      hi[i] = h;
      lo[i] = (__bf16)(xs[i] - (float)h);
    }
    *reinterpret_cast<bf16x8*>(krow + k0) = hi;   // kvsB = bf16(kvs), exact
    bf16x8 bh = *reinterpret_cast<const bf16x8*>(wh + k0);
    bf16x8 bl = *reinterpret_cast<const bf16x8*>(wl + k0);
    acc = __builtin_amdgcn_mfma_f32_16x16x32_bf16(hi, bh, acc, 0, 0, 0);
    acc = __builtin_amdgcn_mfma_f32_16x16x32_bf16(hi, bl, acc, 0, 0, 0);
    acc = __builtin_amdgcn_mfma_f32_16x16x32_bf16(lo, bh, acc, 0, 0, 0);
  }
  const float c = cb[b * NH + r16];               // head = r16 in C layout
#pragma unroll
  for (int r = 0; r < 4; ++r) {
    const int orow = row0 + kgrp * 4 + r;
    float s = acc[r] + c;
    attn[((size_t)b * KL + orow) * NH + r16] = fminf(fmaxf(s, 0.f), 1.f);
  }
}

// ---------- 256x256 / BK=64 bf16 MFMA GEMM, 8-barrier m201-style phases ----------
// 512 threads = 8 waves (2M x 4N); wave tile 128x64. 4 phases/K-tile, each:
//   { ds_read subtile; stage 1 half-tile(t+1); barrier; lgkmcnt(0);
//     sched_barrier(0); setprio(1); 16 MFMA; setprio(0); [vmcnt]; barrier }
// Stage order per tile: p1:Bh0 p2:Bh1 p3:Ah0 p4:Ah1 (2 loads/thread each).
// Counted-vmcnt ledger (per thread; retirement = vmcnt + barrier pair):
//   tile start: outstanding = Ah1(t).
//   p1: +Bh0(t+1)=4; vmcnt(2) after MFMA retires Ah1(t) -> p2's ds_read safe.
//   p2: +Bh1(t+1)=4. p3: +Ah0(t+1)=6.
//   p4: +Ah1(t+1)=8; vmcnt(2) retires B(t+1)+Ah0(t+1) for next p1.
// Never vmcnt(0) mid-loop. T2 swizzle both-sides as verified in R7.
template <bool GATE>
__global__ __launch_bounds__(512, 2) void gemm_nt(const __bf16* __restrict__ A,
                                                  const __bf16* __restrict__ Bt,
                                                  const float* __restrict__ bias,
                                                  const float* __restrict__ gate,
                                                  void* __restrict__ Cp) {
  __shared__ __bf16 As[2][256 * 64];
  __shared__ __bf16 Bs[2][256 * 64];
  const int tid = threadIdx.x;
  const int lane = tid & 63, wid = tid >> 6;
  const int wm = wid >> 2, wn = wid & 3;           // 2 x 4 waves
  const int r16 = lane & 15, kgrp = lane >> 4;
  const int bswz = (blockIdx.x & 7) * 128 + (blockIdx.x >> 3);
  const int m0 = (bswz >> 2) * 256;
  const int n0 = (bswz & 3) * 256;

  const int srow = lane >> 3;
  const int scol = ((lane & 7) ^ srow) * 8;        // pre-swizzled source col

  const int sw0 = ((kgrp) ^ (r16 & 7)) * 8;
  const int sw1 = ((4 + kgrp) ^ (r16 & 7)) * 8;

  f32x4 acc[8][4] = {};   // [mh*4+f][nh*2+g]

#define STAGE_HALF(dstbuf, srcp, base0, h, k0)                                  \
  {                                                                             \
    _Pragma("unroll") for (int j = 0; j < 2; ++j) {                             \
      const int c = (h) * 16 + wid * 2 + j;                                     \
      gload_lds16((srcp) + (size_t)((base0) + c * 8 + srow) * D_ + (k0) + scol, \
                  &(dstbuf)[c * 512]);                                          \
    }                                                                           \
  }

#define LOAD_BV(Bb, sw)                                                         \
  _Pragma("unroll") for (int nh = 0; nh < 2; ++nh)                              \
    _Pragma("unroll") for (int g = 0; g < 2; ++g)                               \
      bv[nh * 2 + g] = *reinterpret_cast<const bf16x8*>(                        \
          &(Bb)[(nh * 128 + wn * 32 + g * 16 + r16) * 64 + (sw)]);

#define LOAD_AV(Ab, mh, sw)                                                     \
  _Pragma("unroll") for (int f = 0; f < 4; ++f)                                 \
    av[f] = *reinterpret_cast<const bf16x8*>(                                   \
        &(Ab)[((mh) * 128 + wm * 64 + f * 16 + r16) * 64 + (sw)]);

#define MFMA_PHASE(mh)                                                          \
  {                                                                             \
    __builtin_amdgcn_s_setprio(1);                                              \
    _Pragma("unroll") for (int f = 0; f < 4; ++f)                               \
      _Pragma("unroll") for (int q = 0; q < 4; ++q)                             \
        acc[(mh) * 4 + f][q] = __builtin_amdgcn_mfma_f32_16x16x32_bf16(         \
            av[f], bv[q], acc[(mh) * 4 + f][q], 0, 0, 0);                       \
    __builtin_amdgcn_s_setprio(0);                                              \
  }

#define WAITLGKM()                                                              \
  asm volatile("s_waitcnt lgkmcnt(0)" ::: "memory");                            \
  __builtin_amdgcn_sched_barrier(0);

  // prologue: tile 0 = Bh0,Bh1,Ah0,Ah1; retire all but Ah1(0).
  STAGE_HALF(Bs[0], Bt, n0, 0, 0);
  STAGE_HALF(Bs[0], Bt, n0, 1, 0);
  STAGE_HALF(As[0], A,  m0, 0, 0);
  STAGE_HALF(As[0], A,  m0, 1, 0);
  asm volatile("s_waitcnt vmcnt(2)" ::: "memory");
  __builtin_amdgcn_s_barrier();

  const int NT = D_ / 64;   // 16
  for (int t = 0; t < NT; ++t) {
    __bf16* Ab = (t & 1) ? As[1] : As[0];
    __bf16* Bb = (t & 1) ? Bs[1] : Bs[0];
    __bf16* An = (t & 1) ? As[0] : As[1];
    __bf16* Bn = (t & 1) ? Bs[0] : Bs[1];
    const int k1 = (t + 1) * 64;
    const bool pf = (t < NT - 1);
    bf16x8 bv[4], av[4];

    // ---- p1: (mh0, kk0); stage Bh0(t+1); retire Ah1(t) ----
    LOAD_BV(Bb, sw0);
    LOAD_AV(Ab, 0, sw0);
    if (pf) STAGE_HALF(Bn, Bt, n0, 0, k1);
    __builtin_amdgcn_s_barrier();
    WAITLGKM();
    MFMA_PHASE(0);
    if (pf) asm volatile("s_waitcnt vmcnt(2)" ::: "memory");
    else    asm volatile("s_waitcnt vmcnt(0)" ::: "memory");
    __builtin_amdgcn_s_barrier();
    // ---- p2: (mh1, kk0); stage Bh1(t+1) ----
    LOAD_AV(Ab, 1, sw0);
    if (pf) STAGE_HALF(Bn, Bt, n0, 1, k1);
    __builtin_amdgcn_s_barrier();
    WAITLGKM();
    MFMA_PHASE(1);
    __builtin_amdgcn_s_barrier();
    // ---- p3: (mh0, kk1); stage Ah0(t+1) ----
    LOAD_BV(Bb, sw1);
    LOAD_AV(Ab, 0, sw1);
    if (pf) STAGE_HALF(An, A, m0, 0, k1);
    __builtin_amdgcn_s_barrier();
    WAITLGKM();
    MFMA_PHASE(0);
    __builtin_amdgcn_s_barrier();
    // ---- p4: (mh1, kk1); stage Ah1(t+1); retire B(t+1)+Ah0(t+1) ----
    LOAD_AV(Ab, 1, sw1);
    if (pf) STAGE_HALF(An, A, m0, 1, k1);
    __builtin_amdgcn_s_barrier();
    WAITLGKM();
    MFMA_PHASE(1);
    if (pf) asm volatile("s_waitcnt vmcnt(2)" ::: "memory");
    __builtin_amdgcn_s_barrier();
  }

  // epilogue. C/D layout: col = lane&15, row = (lane>>4)*4 + reg
#pragma unroll
  for (int mh = 0; mh < 2; ++mh) {
#pragma unroll
    for (int f = 0; f < 4; ++f) {
      const int row0 = m0 + mh * 128 + wm * 64 + f * 16 + kgrp * 4;
#pragma unroll
      for (int nh = 0; nh < 2; ++nh) {
#pragma unroll
        for (int g = 0; g < 2; ++g) {
          const int col = n0 + nh * 128 + wn * 32 + g * 16 + r16;
          const float bc = bias[col];
          const int head = col >> 6;
          f32x4 v = acc[mh * 4 + f][nh * 2 + g];
#pragma unroll
          for (int r = 0; r < 4; ++r) {
            const int row = row0 + r;
            if constexpr (GATE) {
              float gg = gate[(size_t)row * NH + head];
              ((__bf16*)Cp)[(size_t)row * D_ + col] = (__bf16)((v[r] + bc) * gg);
            } else {
              ((float*)Cp)[(size_t)row * D_ + col] = v[r] + bc;
            }
          }
        }
      }
    }
  }
#undef STAGE_HALF
#undef LOAD_BV
#undef LOAD_AV
#undef MFMA_PHASE
#undef WAITLGKM
}

extern "C" void kernel_launch(void* const* d_in, const int* in_sizes, int n_in,
                              void* d_out, int out_size, void* d_ws, size_t ws_size,
                              hipStream_t stream) {
  const float* hs  = (const float*)d_in[0];   // [16,1,1024]
  const float* kvs = (const float*)d_in[1];   // [16,4096,1024]
  const float* Wq  = (const float*)d_in[2];
  const float* bq  = (const float*)d_in[3];
  const float* Wk  = (const float*)d_in[4];
  const float* bk  = (const float*)d_in[5];
  const float* Wv  = (const float*)d_in[6];
  const float* bv  = (const float*)d_in[7];
  const float* Wo  = (const float*)d_in[8];
  const float* bo  = (const float*)d_in[9];
  float* out = (float*)d_out;

  char* w = (char*)d_ws;
  __bf16* ctx  = (__bf16*)w;  w += (size_t)NROWS * D_ * 2;    // 128 MB gated context (bf16)
  float*  attn = (float*)w;   w += (size_t)NROWS * NH * 4;    // 4 MB gate [row][head]
  __bf16* WvB  = (__bf16*)w;  w += (size_t)D_ * D_ * 2;       // 2 MB
  __bf16* WoB  = (__bf16*)w;  w += (size_t)D_ * D_ * 2;       // 2 MB
  __bf16* whi  = (__bf16*)w;  w += (size_t)B_ * NH * D_ * 2;  // 512 KB
  __bf16* wlo  = (__bf16*)w;  w += (size_t)B_ * NH * D_ * 2;  // 512 KB
  float*  qbuf = (float*)w;   w += (size_t)B_ * D_ * 4;       // 64 KB
  float*  cbuf = (float*)w;   w += B_ * NH * 4;               // 1 KB

  // bf16 copy of kvs lives in d_out (128 MB of its 256 MB); written by
  // scores_mfma (== bf16(kvs) exactly), consumed by GEMM1, then fully
  // overwritten by GEMM2's epilogue. No cross-call state.
  __bf16* kvsB = (__bf16*)d_out;

  conv_bf16_kernel<<<1024, 256, 0, stream>>>(Wv, WvB, 262144);
  conv_bf16_kernel<<<1024, 256, 0, stream>>>(Wo, WoB, 262144);
  qproj_kernel<<<64, 256, 0, stream>>>(hs, Wq, bq, qbuf);
  wqeff_kernel<<<dim3(NH, B_), 256, 0, stream>>>(qbuf, Wk, bk, whi, wlo, cbuf);
  scores_mfma_kernel<<<dim3(KL / 64, B_), 256, 0, stream>>>(kvs, whi, wlo, cbuf, attn, kvsB);
  gemm_nt<true ><<<1024, 512, 0, stream>>>(kvsB, WvB, bv, attn, ctx);
  gemm_nt<false><<<1024, 512, 0, stream>>>(ctx, WoB, bo, (const float*)nullptr, (void*)out);
}